// Round 11
// baseline (298.131 us; speedup 1.0000x reference)
//
#include <hip/hip_runtime.h>
#include <stdint.h>

// Problem dims
#define BDIM 8
#define CDIM 32
#define NDIM 512
#define TDIM 168
#define KG   2048          // GEMM K = 4 slices * 512 nodes
#define NJ   43008         // 1344 (b,l) * 32 o   (column order jj = (b*168+l)*32 + o)
#define ALPHA_ 0.05f
#define BETA_  0.95f

typedef __attribute__((ext_vector_type(8))) short short8;
typedef __attribute__((ext_vector_type(4))) float f32x4;
typedef __attribute__((ext_vector_type(2))) float f2v;
typedef __attribute__((ext_vector_type(4))) unsigned short u16x4;

__device__ __forceinline__ unsigned short f2bf(float f) {
  union { float f; unsigned int u; } v; v.f = f;
  unsigned int r = v.u + 0x7fffu + ((v.u >> 16) & 1u);
  return (unsigned short)(r >> 16);
}
__device__ __forceinline__ float bf2f(unsigned short h) {
  union { unsigned int u; float f; } v; v.u = ((unsigned int)h) << 16;
  return v.f;
}
__device__ __forceinline__ void gload_lds16(const void* g, void* l) {
  __builtin_amdgcn_global_load_lds((const __attribute__((address_space(1))) void*)g,
                                   (__attribute__((address_space(3))) void*)l, 16, 0, 0);
}

// ---- prep: row sums of (adp + I) and (adp^T + I) ----
__global__ void gc_prep(const float* __restrict__ adp, float* __restrict__ rs) {
  int v = blockIdx.x, t = threadIdx.x;
  float sA = 0.f, sB = 0.f;
  for (int w = t; w < NDIM; w += 256) { sA += adp[v * NDIM + w]; sB += adp[w * NDIM + v]; }
  __shared__ float red[2][256];
  red[0][t] = sA; red[1][t] = sB; __syncthreads();
  for (int s = 128; s > 0; s >>= 1) {
    if (t < s) { red[0][t] += red[0][t + s]; red[1][t] += red[1][t + s]; }
    __syncthreads();
  }
  if (t == 0) { rs[v] = 1.f + red[0][0]; rs[NDIM + v] = 1.f + red[1][0]; }
}

// ---- build A (slice 0) and A' (slice 2) into chunked G2[(k>>3)][n][8], plus fp32 copies ----
__global__ void gc_build(const float* __restrict__ adp, const float* __restrict__ rs,
                         float* __restrict__ Af, unsigned short* __restrict__ G2) {
  int v = blockIdx.x, t = threadIdx.x;
  float ra = 1.f / rs[v], rb = 1.f / rs[NDIM + v];
  for (int w = t; w < NDIM; w += 256) {
    float d = (v == w) ? 1.f : 0.f;
    float a  = (adp[v * NDIM + w] + d) * ra;   // A[v][w]
    float a2 = (adp[w * NDIM + v] + d) * rb;   // A'[v][w]
    Af[(size_t)v * NDIM + w] = a;
    Af[(size_t)NDIM * NDIM + (size_t)v * NDIM + w] = a2;
    G2[(size_t)(((0 * 64) + (w >> 3)) * 512 + v) * 8 + (w & 7)] = f2bf(a);
    G2[(size_t)(((2 * 64) + (w >> 3)) * 512 + v) * 8 + (w & 7)] = f2bf(a2);
  }
}

// ---- A^2 (slice 1) and A'^2 (slice 3) into G2; 512 blocks of 32x32 tiles ----
__global__ __launch_bounds__(256, 4) void gc_sq2(const float* __restrict__ Af,
                                                 unsigned short* __restrict__ G2) {
  int bid = blockIdx.x;
  int mat = bid >> 8, tile = bid & 255;
  int v0 = (tile >> 4) * 32, w0 = (tile & 15) * 32;
  const float* M = Af + (size_t)mat * NDIM * NDIM;
  __shared__ float T1[64][33];
  __shared__ float T2[64][33];
  int t = threadIdx.x;
  int ty = t >> 4, tx = t & 15;
  float a00 = 0.f, a01 = 0.f, a10 = 0.f, a11 = 0.f;
  for (int u0 = 0; u0 < NDIM; u0 += 64) {
    #pragma unroll
    for (int q = 0; q < 8; ++q) {
      int id = q * 256 + t;
      int c = id & 63, r = id >> 6;
      T1[c][r] = M[(size_t)(v0 + r) * NDIM + u0 + c];
      int u = id >> 5, w = id & 31;
      T2[u][w] = M[(size_t)(u0 + u) * NDIM + w0 + w];
    }
    __syncthreads();
    for (int u = 0; u < 64; ++u) {
      f2v a = *(const f2v*)&T1[u][ty * 2];
      f2v b = *(const f2v*)&T2[u][tx * 2];
      a00 += a[0] * b[0]; a01 += a[0] * b[1];
      a10 += a[1] * b[0]; a11 += a[1] * b[1];
    }
    __syncthreads();
  }
  int sl = mat ? 3 : 1;
  int v = v0 + ty * 2, w = w0 + tx * 2;
  size_t cb = (size_t)(sl * 64 + (w >> 3)) * 512;
  size_t cb1 = (size_t)(sl * 64 + ((w + 1) >> 3)) * 512;
  G2[(cb  + v    ) * 8 + (w & 7)]       = f2bf(a00);
  G2[(cb1 + v    ) * 8 + ((w + 1) & 7)] = f2bf(a01);
  G2[(cb  + v + 1) * 8 + (w & 7)]       = f2bf(a10);
  G2[(cb1 + v + 1) * 8 + ((w + 1) & 7)] = f2bf(a11);
}

// ---- folded channel-mix matrices, bf16: Ub[160][32] rows = {U1,U2,V1,V2,U0'}; bias = b1+b2 ----
__global__ void gc_ucat(const float* __restrict__ W1, const float* __restrict__ b1,
                        const float* __restrict__ W2, const float* __restrict__ b2,
                        unsigned short* __restrict__ Ub, float* __restrict__ bias) {
  int t = threadIdx.x;
  for (int idx = t; idx < 160 * 32; idx += 256) {
    int ko = idx >> 5, c = idx & 31, o = ko & 31, s = ko >> 5;
    float v;
    if (s == 0)      v = BETA_ * (W1[o * 96 + 32 + c] + ALPHA_ * W1[o * 96 + 64 + c]);
    else if (s == 1) v = BETA_ * BETA_ * W1[o * 96 + 64 + c];
    else if (s == 2) v = BETA_ * (W2[o * 96 + 32 + c] + ALPHA_ * W2[o * 96 + 64 + c]);
    else if (s == 3) v = BETA_ * BETA_ * W2[o * 96 + 64 + c];
    else             v = W1[o * 96 + c] + ALPHA_ * (W1[o * 96 + 32 + c] + W1[o * 96 + 64 + c])
                       + W2[o * 96 + c] + ALPHA_ * (W2[o * 96 + 32 + c] + W2[o * 96 + 64 + c]);
    Ub[idx] = f2bf(v);
  }
  if (t < 32) bias[t] = b1[t] + b2[t];
}

// ---- channel-mix via MFMA, direct stores in (b,l,o)-major column order ----
// Pg[kbg 0..320)[jj][8w]; slices 0..3 = GEMM B-panel, slice 4 = identity (old R0).
// grid 1024 = 8 b * 32 wt(16 w) * 4 lq(42 l); 256 threads (4 waves)
__global__ __launch_bounds__(256, 2) void gc_mix6(const float* __restrict__ x,
    const unsigned short* __restrict__ Ub, unsigned short* __restrict__ Pg) {
  __shared__ __align__(16) unsigned short xs[26880];  // [42 ll][16 w'][40 c pad]
  int bid = blockIdx.x;
  int lq = bid & 3, wt = (bid >> 2) & 31, b = bid >> 7;
  int l0 = lq * 42, w0 = wt * 16;
  int tid = threadIdx.x, wv = tid >> 6, lane = tid & 63;
  int l15 = lane & 15, hi = lane >> 4;

  // stage x[b][:][w0..w0+16)[l0..l0+42) -> xs (coalesced reads, swizzled 2B writes)
  #pragma unroll 4
  for (int e = 0; e < 84; ++e) {
    int id = e * 256 + tid;
    int c = id / 672, rem = id - c * 672;
    int w = rem / 42, ll = rem - w * 42;
    float v = x[(size_t)((b * 32 + c) * 512 + w0 + w) * 168 + l0 + ll];
    xs[(ll * 16 + (w ^ (ll & 15))) * 40 + c] = f2bf(v);
  }
  __syncthreads();

  // B-operand fragments from Ub (col=l15 -> o, k=hi*8.. -> c)
  short8 uF[10];
  #pragma unroll
  for (int mt = 0; mt < 10; ++mt)
    uF[mt] = *(const short8*)(Ub + (size_t)(mt * 16 + l15) * 32 + hi * 8);

  for (int i = 0; i < 11; ++i) {
    int li = wv + 4 * i;
    if (li >= 42) break;
    int l = l0 + li;
    short8 xf = *(const short8*)&xs[(li * 16 + (l15 ^ (li & 15))) * 40 + hi * 8];
    size_t jbase = (size_t)(b * 168 + l) * 32;
    #pragma unroll
    for (int mt = 0; mt < 10; ++mt) {
      f32x4 z = {0.f, 0.f, 0.f, 0.f};
      f32x4 p = __builtin_amdgcn_mfma_f32_16x16x32_bf16(xf, uF[mt], z, 0, 0, 0);
      size_t kbg = (size_t)((mt >> 1) * 64 + wt * 2 + (hi >> 1));
      size_t jj = jbase + ((mt & 1) << 4) + l15;
      u16x4 pk = { f2bf(p[0]), f2bf(p[1]), f2bf(p[2]), f2bf(p[3]) };
      *(u16x4*)(Pg + (kbg * NJ + jj) * 8 + (hi & 1) * 4) = pk;
    }
  }
}

// ---- main GEMM: B-direct-to-register, A-only LDS ----
// C[512 n][43008 jj] = G[512][2048] * P; epilogue adds P4 + bias via LDS slab.
// 672 blocks (2 mt * 336 jt), 256 threads = 4 waves, wave tile 64x128 (wm = wid):
// A-tile read from LDS exactly once (no cross-wave redundancy); B fragments loaded
// per-lane straight from Pg (L2/L3) with register double-buffer (bA/bB named sets).
// A pair-staged (2 K-tiles) into ping-pong 32KB halves: 1 barrier + 1 vmcnt(16)
// per 2 K-tiles. LDS traffic/block-iter: 72KB -> 32KB.
__global__ __launch_bounds__(256, 2) void gc_gemm11(const unsigned short* __restrict__ G2,
    const unsigned short* __restrict__ Pg, const float* __restrict__ bias,
    float* __restrict__ out) {
  int bid = blockIdx.x;
  int swz = (bid & 7) * 84 + (bid >> 3);   // XCD-chunked bijective swizzle (672 = 8*84)
  int mt = swz & 1, jt = swz >> 1;         // mt fastest: B-panel pair adjacent on same XCD
  int n0 = mt * 256, jj0 = jt * 128;

  __shared__ __align__(16) unsigned short SH[32768];   // 64 KB: 2 halves x 2 tiles x 8192
  int tid = threadIdx.x, lane = tid & 63, wid = tid >> 6;
  int l15 = lane & 15, hi = lane >> 4;

  // A staging: 4 chunks/thread/tile; offA in shorts (per-thread, constant)
  int offA[4], dA[4];
  #pragma unroll
  for (int q = 0; q < 4; ++q) {
    int f = q * 256 + tid;                 // kb = f>>8, nloc = f&255
    offA[q] = (((f >> 8) * 512) + n0 + (f & 255)) * 8;
    dA[q] = f * 8;
  }
  const size_t strideA = 4 * 512 * 8;      // shorts per K-32 tile
  const size_t strideB = (size_t)4 * NJ * 8;

  // B per-lane bases: bA stream (even tiles), bB stream (odd tiles)
  const unsigned short* pBA = Pg + ((size_t)hi * NJ + jj0 + l15) * 8;
  const unsigned short* pBB = pBA + strideB;

  f32x4 acc[4][8] = {};
  short8 bA[8], bB[8];

  // prologue: stage A(0),A(1) -> half0; load B(0)->bA, B(1)->bB
  #pragma unroll
  for (int q = 0; q < 4; ++q) {
    gload_lds16(G2 + offA[q], SH + dA[q]);
    gload_lds16(G2 + strideA + offA[q], SH + 8192 + dA[q]);
  }
  #pragma unroll
  for (int nj = 0; nj < 8; ++nj) bA[nj] = *(const short8*)(pBA + nj * 128);
  pBA += 2 * strideB;
  #pragma unroll
  for (int nj = 0; nj < 8; ++nj) bB[nj] = *(const short8*)(pBB + nj * 128);
  pBB += 2 * strideB;

  int aoffs = (wid * 64 + l15) * 8;        // + mi*128 + hi*2048

  for (int s = 0; s < 32; ++s) {
    // A-pair for this body must be LDS-visible; 16 newest (2 B-sets) may stay in flight
    asm volatile("s_waitcnt vmcnt(16)" ::: "memory");
    __builtin_amdgcn_s_barrier();
    const int h = s & 1;
    const unsigned short* apE = SH + h * 16384;          // tile 2s
    const unsigned short* apO = apE + 8192;              // tile 2s+1

    if (s < 31) {                          // stage A(2s+2), A(2s+3) -> other half
      size_t base = (size_t)(2 * s + 2) * strideA;
      #pragma unroll
      for (int q = 0; q < 4; ++q) {
        gload_lds16(G2 + base + offA[q], SH + (h ^ 1) * 16384 + dA[q]);
        gload_lds16(G2 + base + strideA + offA[q], SH + (h ^ 1) * 16384 + 8192 + dA[q]);
      }
    }

    // ---- even half: tile 2s with bA ----
    {
      short8 aF[4];
      #pragma unroll
      for (int mi = 0; mi < 4; ++mi)
        aF[mi] = *(const short8*)&apE[hi * 2048 + aoffs + mi * 128];
      __builtin_amdgcn_s_setprio(1);
      #pragma unroll
      for (int mi = 0; mi < 4; ++mi)
        #pragma unroll
        for (int nj = 0; nj < 8; ++nj)
          acc[mi][nj] = __builtin_amdgcn_mfma_f32_16x16x32_bf16(aF[mi], bA[nj], acc[mi][nj], 0, 0, 0);
      __builtin_amdgcn_s_setprio(0);
    }
    if (s < 31) {                          // refill bA with B(2s+2)
      #pragma unroll
      for (int nj = 0; nj < 8; ++nj) bA[nj] = *(const short8*)(pBA + nj * 128);
      pBA += 2 * strideB;
    }

    // ---- odd half: tile 2s+1 with bB ----
    {
      short8 aF[4];
      #pragma unroll
      for (int mi = 0; mi < 4; ++mi)
        aF[mi] = *(const short8*)&apO[hi * 2048 + aoffs + mi * 128];
      __builtin_amdgcn_s_setprio(1);
      #pragma unroll
      for (int mi = 0; mi < 4; ++mi)
        #pragma unroll
        for (int nj = 0; nj < 8; ++nj)
          acc[mi][nj] = __builtin_amdgcn_mfma_f32_16x16x32_bf16(aF[mi], bB[nj], acc[mi][nj], 0, 0, 0);
      __builtin_amdgcn_s_setprio(0);
    }
    if (s < 31) {                          // refill bB with B(2s+3)
      #pragma unroll
      for (int nj = 0; nj < 8; ++nj) bB[nj] = *(const short8*)(pBB + nj * 128);
      pBB += 2 * strideB;
    }
  }

  // ---- epilogue: 4 slabs of 64 n (one per wave); LDS transpose; out = C + P4 + bias ----
  int bl0 = jt * 4;                        // 4 consecutive (b,l), same b (168%4==0)
  int bq = bl0 / 168, l0g = bl0 - bq * 168;
  float* Cs = (float*)SH;                  // 64*132*4 = 33.8KB <= 64KB
  int o = tid & 31, nl8 = tid >> 5;
  float bs = bias[o];
  __syncthreads();
  for (int sl = 0; sl < 4; ++sl) {
    if (wid == sl) {
      #pragma unroll
      for (int mi = 0; mi < 4; ++mi)
        #pragma unroll
        for (int nj = 0; nj < 8; ++nj) {
          int row = mi * 16 + hi * 4;
          int col = nj * 16 + l15;
          #pragma unroll
          for (int r = 0; r < 4; ++r)
            Cs[(row + r) * 132 + col] = acc[mi][nj][r];
        }
    }
    __syncthreads();
    int n_g0 = n0 + sl * 64 + nl8 * 8;
    const unsigned short* p4c =
        Pg + (((size_t)256 + (n_g0 >> 3)) * NJ + (size_t)bl0 * 32 + o) * 8;
    short8 pv0 = *(const short8*)(p4c);
    short8 pv1 = *(const short8*)(p4c + 256);
    short8 pv2 = *(const short8*)(p4c + 512);
    short8 pv3 = *(const short8*)(p4c + 768);
    #pragma unroll
    for (int q = 0; q < 8; ++q) {
      int nr = sl * 0 + nl8 * 8 + q;       // slab-local row
      int n_g = n_g0 + q;
      float v0 = Cs[nr * 132 +  0 + o] + bf2f((unsigned short)pv0[q]) + bs;
      float v1 = Cs[nr * 132 + 32 + o] + bf2f((unsigned short)pv1[q]) + bs;
      float v2 = Cs[nr * 132 + 64 + o] + bf2f((unsigned short)pv2[q]) + bs;
      float v3 = Cs[nr * 132 + 96 + o] + bf2f((unsigned short)pv3[q]) + bs;
      f32x4 vv = {v0, v1, v2, v3};
      *(f32x4*)(out + ((size_t)(bq * 32 + o) * 512 + n_g) * 168 + l0g) = vv;
    }
    __syncthreads();
  }
}

extern "C" void kernel_launch(void* const* d_in, const int* in_sizes, int n_in,
                              void* d_out, int out_size, void* d_ws, size_t ws_size,
                              hipStream_t stream) {
  const float* x   = (const float*)d_in[0];
  const float* adp = (const float*)d_in[1];
  const float* W1  = (const float*)d_in[2];
  const float* b1  = (const float*)d_in[3];
  const float* W2  = (const float*)d_in[4];
  const float* b2  = (const float*)d_in[5];
  float* out = (float*)d_out;

  char* w = (char*)d_ws;
  unsigned short* Pg  = (unsigned short*)(w);                  // 220,200,960 B (5 slices)
  unsigned short* G2  = (unsigned short*)(w + 220200960ULL);   //   2,097,152 B
  float* Af           = (float*)(w + 222298112ULL);            //   2,097,152 B
  float* rs           = (float*)(w + 224395264ULL);            //       4,096 B
  unsigned short* Ub  = (unsigned short*)(w + 224399360ULL);   //      16,384 B (10,240 used)
  float* bias         = (float*)(w + 224415744ULL);            //         128 B
  if (ws_size < 224415872ULL) return;                          // need ~214 MiB

  gc_prep<<<512, 256, 0, stream>>>(adp, rs);
  gc_build<<<512, 256, 0, stream>>>(adp, rs, Af, G2);
  gc_sq2<<<512, 256, 0, stream>>>(Af, G2);
  gc_ucat<<<1, 256, 0, stream>>>(W1, b1, W2, b2, Ub, bias);
  gc_mix6<<<1024, 256, 0, stream>>>(x, Ub, Pg);
  gc_gemm11<<<672, 256, 0, stream>>>(G2, Pg, bias, out);
}